// Round 8
// baseline (195.997 us; speedup 1.0000x reference)
//
#include <hip/hip_runtime.h>
#include <math.h>

// TranAD fused forward, 2 blocks per batch element (grid=256, 1024 thr).
// Round-8: phase-pipelining. r5/r7 showed time is NOT LDS-throughput-bound
// (halving GEMM LDS instrs changed nothing) -- it's phase-serialization:
// ~30 barrier phases/pass, weight staging serial between GEMMs. Fix:
// triple-buffered weight staging (B0/B1/B2, 64x68 each) so every compute
// interval also stages the NEXT phase's weights (idle waves overlap);
// batched kv_wait loads (issue both, one vmcnt). GEMM/attn inner loops
// identical to r7. Exchange via sc0 sc1 IF$-coherent ops (proven r5).
// Co-residency: 152KB LDS > 80KB => 1 block/CU => all 256 blocks resident.
// Flags start 0 each iteration (harness memsets workspace).

#define TPB 1024
#define RH 50
#define SQ32 5.656854249492381f

typedef float v2f __attribute__((ext_vector_type(2)));
typedef float v4f __attribute__((ext_vector_type(4)));

#ifndef __has_builtin
#define __has_builtin(x) 0
#endif
#if __has_builtin(__builtin_amdgcn_exp2f)
#define EXP2(x) __builtin_amdgcn_exp2f(x)
#else
#define EXP2(x) exp2f(x)
#endif

struct KParams { const void* p[36]; };

// ---- stage W[MC][K] (row-major) transposed into Ws[k*WP + m] ----
template<int K, int MC, int WP>
__device__ __forceinline__ void ldwp(const float* __restrict__ Wt, float* __restrict__ Ws, int tid)
{
    for (int i = tid; i < MC * K; i += TPB) {
        int m = i / K, k = i - m * K;
        Ws[k * WP + m] = Wt[i];
    }
}

// ---- 2 rows x 4 cols, x as v4f, weights LDS [k][*] pitch WP ----
template<int K, int WP>
__device__ __forceinline__ void gemm_dual24(const float* __restrict__ x0,
                                            const float* __restrict__ x1,
                                            const float* __restrict__ w, v2f acc[4])
{
#pragma unroll 4
    for (int kk = 0; kk < K / 4; ++kk) {
        v4f xa = *reinterpret_cast<const v4f*>(x0 + 4 * kk);
        v4f xb = *reinterpret_cast<const v4f*>(x1 + 4 * kk);
#pragma unroll
        for (int j = 0; j < 4; ++j) {
            v4f wv = *reinterpret_cast<const v4f*>(w + (size_t)(4 * kk + j) * WP);
            v2f xj = {xa[j], xb[j]};
#pragma unroll
            for (int c = 0; c < 4; ++c) {
                v2f wc = {wv[c], wv[c]};
                acc[c] = __builtin_elementwise_fma(xj, wc, acc[c]);
            }
        }
    }
}

// ---- 1 row x 4 cols, x as v4f ----
template<int K, int WP>
__device__ __forceinline__ void gemm14v(const float* __restrict__ x,
                                        const float* __restrict__ w, float acc[4])
{
#pragma unroll 4
    for (int kk = 0; kk < K / 4; ++kk) {
        v4f xv = *reinterpret_cast<const v4f*>(x + 4 * kk);
#pragma unroll
        for (int j = 0; j < 4; ++j) {
            v4f wv = *reinterpret_cast<const v4f*>(w + (size_t)(4 * kk + j) * WP);
#pragma unroll
            for (int c = 0; c < 4; ++c) acc[c] = fmaf(xv[j], wv[c], acc[c]);
        }
    }
}

// ---------------------------------------------------------------------------
// KV projection: 800 thr (tid<400: K from BK, 400..799: V from BV), 2 rows
// each. Writes interleaved KVs[h][101] (k->xy, v->zw) + sc0sc1 exchange store.
// ---------------------------------------------------------------------------
__device__ __forceinline__ void kv_gemm(const float* __restrict__ Xkv,
    const float* __restrict__ BK, const float* __restrict__ BV,
    const float* __restrict__ Bqkv, int b, int base,
    float4* __restrict__ KVs, float4* __restrict__ Gx, int tid)
{
    if (tid >= 800) return;
    const int isV = tid >= 400;
    const int u = tid - (isV ? 400 : 0);
    const int r0 = u >> 4, cg = u & 15;
    v2f acc[4] = {};
    gemm_dual24<64, 68>(Xkv + r0 * 68, Xkv + (r0 + 25) * 68,
                        (isV ? BV : BK) + 4 * cg, acc);
    v4f bb = *reinterpret_cast<const v4f*>(Bqkv + (isV ? 128 : 64) + 4 * cg);
    const int h0 = 2 * cg;
    const int off = isV ? 2 : 0;
#pragma unroll
    for (int rr = 0; rr < 2; ++rr) {
        int sg = base + r0 + 25 * rr;
        v2f p0 = {acc[0][rr] + bb[0], acc[1][rr] + bb[1]};
        v2f p1 = {acc[2][rr] + bb[2], acc[3][rr] + bb[3]};
        *reinterpret_cast<v2f*>(reinterpret_cast<float*>(KVs + h0 * 101 + sg) + off) = p0;
        *reinterpret_cast<v2f*>(reinterpret_cast<float*>(KVs + (h0 + 1) * 101 + sg) + off) = p1;
        float* g0 = reinterpret_cast<float*>(Gx + ((size_t)b * 100 + sg) * 32 + h0) + off;
        float* g1 = reinterpret_cast<float*>(Gx + ((size_t)b * 100 + sg) * 32 + h0 + 1) + off;
        asm volatile("global_store_dwordx2 %0, %1, off sc0 sc1" :: "v"(g0), "v"(p0) : "memory");
        asm volatile("global_store_dwordx2 %0, %1, off sc0 sc1" :: "v"(g1), "v"(p1) : "memory");
    }
}

// drain own sc0sc1 stores, barrier, raise flag
__device__ __forceinline__ void flag_pub(int* flagme, int st, int tid)
{
    asm volatile("s_waitcnt vmcnt(0)" ::: "memory");
    __syncthreads();
    if (tid == 0)
        asm volatile("global_store_dword %0, %1, off sc0 sc1" :: "v"(flagme), "v"(st) : "memory");
}

// q projection, 400 thr, 2 rows each -> R1 (weights pitch 68, chunk 0 bias)
__device__ __forceinline__ void q_gemm(const float* __restrict__ Xq,
    const float* __restrict__ BW, const float* __restrict__ Bqkv,
    float* __restrict__ Q, int tid)
{
    if (tid >= 400) return;
    const int r0 = tid >> 4, cg = tid & 15;
    v2f acc[4] = {};
    gemm_dual24<64, 68>(Xq + r0 * 68, Xq + (r0 + 25) * 68, BW + 4 * cg, acc);
    v4f bb = *reinterpret_cast<const v4f*>(Bqkv + 4 * cg);
#pragma unroll
    for (int rr = 0; rr < 2; ++rr)
        *reinterpret_cast<v4f*>(Q + (r0 + 25 * rr) * 68 + 4 * cg) =
            (v4f){acc[0][rr] + bb[0], acc[1][rr] + bb[1],
                  acc[2][rr] + bb[2], acc[3][rr] + bb[3]};
}

// spin (relaxed sc0sc1), then pull partner half: both loads issued, ONE vmcnt
__device__ __forceinline__ void kv_wait(const int* flagpt, int st,
    const float4* __restrict__ Gx, int b, int pbase,
    float4* __restrict__ KVs, int tid)
{
    if (tid == 0) {
        int f;
        for (;;) {
            asm volatile("global_load_dword %0, %1, off sc0 sc1\n\ts_waitcnt vmcnt(0)"
                         : "=v"(f) : "v"(flagpt) : "memory");
            if (f >= st) break;
            __builtin_amdgcn_s_sleep(8);
        }
    }
    __syncthreads();
    const int i2 = tid + 1024;
    v4f a1, a2;
    const float4* p1 = Gx + ((size_t)b * 100 + pbase + (tid >> 5)) * 32 + (tid & 31);
    asm volatile("global_load_dwordx4 %0, %1, off sc0 sc1" : "=v"(a1) : "v"(p1) : "memory");
    if (i2 < 1600) {
        const float4* p2 = Gx + ((size_t)b * 100 + pbase + (i2 >> 5)) * 32 + (i2 & 31);
        asm volatile("global_load_dwordx4 %0, %1, off sc0 sc1" : "=v"(a2) : "v"(p2) : "memory");
    }
    asm volatile("s_waitcnt vmcnt(0)" ::: "memory");
    *reinterpret_cast<v4f*>(KVs + (tid & 31) * 101 + pbase + (tid >> 5)) = a1;
    if (i2 < 1600)
        *reinterpret_cast<v4f*>(KVs + (i2 & 31) * 101 + pbase + (i2 >> 5)) = a2;
    __syncthreads();
}

// attention: own 50 q-rows, full 100-key KV. task = (head, 4-query group)
__device__ __forceinline__ void attn_block(float* __restrict__ Q,
                                           const float4* __restrict__ KVs, int tid)
{
    if (tid < 416) {                           // 32 heads x 13 groups
        const int h = tid / 13;
        const int g = tid - 13 * h;
        const int lq0 = 4 * g;
        const float4* kv = KVs + h * 101;
        const float SCALE = 0.7071067811865476f * 1.4426950408889634f;  // /sqrt(2)*log2e
        float q0[4], q1[4];
#pragma unroll
        for (int j = 0; j < 4; ++j) {
            if (lq0 + j < RH) {
                float2 qv = *reinterpret_cast<const float2*>(Q + (lq0 + j) * 68 + 2 * h);
                q0[j] = qv.x * SCALE; q1[j] = qv.y * SCALE;
            } else { q0[j] = 0.f; q1[j] = 0.f; }
        }
        float mx[4] = {-1e30f, -1e30f, -1e30f, -1e30f};
#pragma unroll 4
        for (int s = 0; s < 100; ++s) {
            float4 k = kv[s];
#pragma unroll
            for (int j = 0; j < 4; ++j)
                mx[j] = fmaxf(mx[j], fmaf(q0[j], k.x, q1[j] * k.y));
        }
        float sum[4] = {0, 0, 0, 0}, a0[4] = {0, 0, 0, 0}, a1[4] = {0, 0, 0, 0};
#pragma unroll 4
        for (int s = 0; s < 100; ++s) {
            float4 k = kv[s];
#pragma unroll
            for (int j = 0; j < 4; ++j) {
                float e = EXP2(fmaf(q0[j], k.x, fmaf(q1[j], k.y, -mx[j])));
                sum[j] += e;
                a0[j] = fmaf(e, k.z, a0[j]);
                a1[j] = fmaf(e, k.w, a1[j]);
            }
        }
#pragma unroll
        for (int j = 0; j < 4; ++j) {
            if (lq0 + j < RH) {
                float inv = 1.f / sum[j];
                *reinterpret_cast<float2*>(Q + (lq0 + j) * 68 + 2 * h) =
                    make_float2(a0[j] * inv, a1[j] * inv);
            }
        }
    }
}

// out-projection + residual in place, 400 thr, 2 rows each (pitch 68)
__device__ __forceinline__ void out_res(const float* __restrict__ Ain,
    const float* __restrict__ BW, const float* __restrict__ Bi,
    float* __restrict__ Sres, int tid)
{
    if (tid >= 400) return;
    const int r0 = tid >> 4, cg = tid & 15;
    v2f acc[4] = {};
    gemm_dual24<64, 68>(Ain + r0 * 68, Ain + (r0 + 25) * 68, BW + 4 * cg, acc);
    v4f bb = *reinterpret_cast<const v4f*>(Bi + 4 * cg);
#pragma unroll
    for (int rr = 0; rr < 2; ++rr) {
        float* sp = Sres + (r0 + 25 * rr) * 68 + 4 * cg;
        v4f s0 = *reinterpret_cast<v4f*>(sp);
        *reinterpret_cast<v4f*>(sp) =
            (v4f){acc[0][rr] + bb[0] + s0[0], acc[1][rr] + bb[1] + s0[1],
                  acc[2][rr] + bb[2] + s0[2], acc[3][rr] + bb[3] + s0[3]};
    }
}

// ---------------------------------------------------------------------------
__global__ __launch_bounds__(TPB) void k_fused(KParams prm, float* __restrict__ outp,
    float4* __restrict__ kvx0, float4* __restrict__ kvx1, int* __restrict__ flags)
{
    __shared__ float R0[RH * 68];        // s / mem
    __shared__ float R1[RH * 68];        // q / attn-out
    __shared__ float R3[RH * 68];        // t
    __shared__ float4 KVs[32 * 101];     // full-seq KV interleaved (k.xy, v.zw)
    __shared__ float B0[64 * 68];        // weight buffers (triple-buffered)
    __shared__ float B1[64 * 68];
    __shared__ float B2[64 * 68];
    __shared__ float Hs[RH * 20];
    __shared__ float X1s[RH * 36];

    const int tid = threadIdx.x;
    const int b = blockIdx.x & 127;
    const int half = blockIdx.x >> 7;
    const int base = half * RH;
    const int pbase = RH - base;
    int* flagme = flags + (b * 2 + half) * 32;
    int* flagpt = flags + (b * 2 + 1 - half) * 32;

    const float* src = (const float*)prm.p[0];
    const float* tgt = (const float*)prm.p[1];

    for (int pass = 0; pass < 2; ++pass) {
        const float* Wq_enc = (const float*)prm.p[2];
        const float* Beq    = (const float*)prm.p[3];
        const float* Wo_enc = (const float*)prm.p[4];
        const float* Beo    = (const float*)prm.p[5];
        const float* Wel1   = (const float*)prm.p[22];
        const float* Bel1   = (const float*)prm.p[23];
        const float* Wel2   = (const float*)prm.p[24];
        const float* Bel2   = (const float*)prm.p[25];
        const float* Wsa    = (const float*)prm.p[pass ? 14 : 6];
        const float* Bsa    = (const float*)prm.p[pass ? 15 : 7];
        const float* Wsao   = (const float*)prm.p[pass ? 16 : 8];
        const float* Bsao   = (const float*)prm.p[pass ? 17 : 9];
        const float* Wca    = (const float*)prm.p[pass ? 18 : 10];
        const float* Bca    = (const float*)prm.p[pass ? 19 : 11];
        const float* Wcao   = (const float*)prm.p[pass ? 20 : 12];
        const float* Bcao   = (const float*)prm.p[pass ? 21 : 13];
        const float* Wdl1   = (const float*)prm.p[pass ? 30 : 26];
        const float* Bdl1   = (const float*)prm.p[pass ? 31 : 27];
        const float* Wdl2   = (const float*)prm.p[pass ? 32 : 28];
        const float* Bdl2   = (const float*)prm.p[pass ? 33 : 29];
        const float* Wf     = (const float*)prm.p[34];
        const float* Bf     = (const float*)prm.p[35];
        float* outx = outp + (pass ? 409600 : 0);

        __syncthreads();     // X1s (prev head) / R0,R3 reuse / buffers free

        // ---- build s -> R0, tile tgt -> R3  |  stage Kenc->B0, Venc->B1 ----
        for (int i = tid; i < RH * 64; i += TPB) {
            int l = i >> 6, d = i & 63;
            int lg = base + l;
            float sv = src[((size_t)lg * 128 + b) * 32 + (d & 31)];
            float v;
            if (d < 32) v = sv;
            else if (pass == 0) v = 0.f;
            else { float df = X1s[l * 36 + (d - 32)] - sv; v = df * df; }
            float div = __expf((float)d * -0.14391156831212787f);
            float pe = 1.4142135623730951f * __sinf((float)lg * div + 0.7853981633974483f);
            R0[l * 68 + d] = v * SQ32 + pe;
        }
        for (int i = tid; i < RH * 8; i += TPB) {
            int l = i >> 3, q4 = i & 7;
            int lg = base + l;
            float4 tv = *reinterpret_cast<const float4*>(tgt + ((size_t)lg * 128 + b) * 32 + 4 * q4);
            *reinterpret_cast<float4*>(R3 + l * 68 + 4 * q4) = tv;
            *reinterpret_cast<float4*>(R3 + l * 68 + 32 + 4 * q4) = tv;
        }
        ldwp<64, 64, 68>(Wq_enc + 4096, B0, tid);
        ldwp<64, 64, 68>(Wq_enc + 8192, B1, tid);
        __syncthreads();

        // ================= ENCODER =================
        {
            int st = pass * 3 + 1;
            float4* Gx = (st & 1) ? kvx1 : kvx0;
            kv_gemm(R0, B0, B1, Beq, b, base, KVs, Gx, tid);
            ldwp<64, 64, 68>(Wq_enc, B2, tid);           // Q weights
            flag_pub(flagme, st, tid);                    // vmcnt + bar + flag
            q_gemm(R0, B2, Beq, R1, tid);
            ldwp<64, 64, 68>(Wo_enc, B0, tid);            // OUT weights
            kv_wait(flagpt, st, Gx, b, pbase, KVs, tid);  // spin,bar,pull,bar
            attn_block(R1, KVs, tid);
            ldwp<64, 16, 20>(Wel1, B1, tid);              // FFN1 weights
            __syncthreads();
            out_res(R1, B0, Beo, R0, tid);
            ldwp<16, 64, 68>(Wel2, B2, tid);              // FFN2 weights
            __syncthreads();
            // FFN1: R0 -> Hs  |  stage Ksa->B0
            if (tid < 200) {
                const int r = tid >> 2, c4 = tid & 3;
                float a[4] = {0, 0, 0, 0};
                gemm14v<64, 20>(R0 + r * 68, B1 + 4 * c4, a);
                v4f bb = *reinterpret_cast<const v4f*>(Bel1 + 4 * c4);
                *reinterpret_cast<v4f*>(Hs + r * 20 + 4 * c4) =
                    (v4f){a[0] + bb[0], a[1] + bb[1], a[2] + bb[2], a[3] + bb[3]};
            }
            ldwp<64, 64, 68>(Wsa + 4096, B0, tid);
            __syncthreads();
            // FFN2: Hs -> R0 (+res)  |  stage Vsa->B1
            if (tid < 400) {
                const int r0 = tid >> 4, cg = tid & 15;
                v2f acc[4] = {};
                gemm_dual24<16, 68>(Hs + r0 * 20, Hs + (r0 + 25) * 20, B2 + 4 * cg, acc);
                v4f bb = *reinterpret_cast<const v4f*>(Bel2 + 4 * cg);
#pragma unroll
                for (int rr = 0; rr < 2; ++rr) {
                    float* xp = R0 + (r0 + 25 * rr) * 68 + 4 * cg;
                    v4f u = *reinterpret_cast<v4f*>(xp);
                    *reinterpret_cast<v4f*>(xp) =
                        (v4f){acc[0][rr] + bb[0] + u[0], acc[1][rr] + bb[1] + u[1],
                              acc[2][rr] + bb[2] + u[2], acc[3][rr] + bb[3] + u[3]};
                }
            }
            ldwp<64, 64, 68>(Wsa + 8192, B1, tid);
            __syncthreads();
        }

        // ================= DECODER SELF-ATTN =================
        {
            int st = pass * 3 + 2;
            float4* Gx = (st & 1) ? kvx1 : kvx0;
            kv_gemm(R3, B0, B1, Bsa, b, base, KVs, Gx, tid);
            ldwp<64, 64, 68>(Wsa, B2, tid);               // Qsa
            flag_pub(flagme, st, tid);
            q_gemm(R3, B2, Bsa, R1, tid);
            ldwp<64, 64, 68>(Wsao, B0, tid);              // OUTsa
            kv_wait(flagpt, st, Gx, b, pbase, KVs, tid);
            attn_block(R1, KVs, tid);
            ldwp<64, 64, 68>(Wca + 4096, B1, tid);        // Kca
            __syncthreads();
            out_res(R1, B0, Bsao, R3, tid);
            ldwp<64, 64, 68>(Wca + 8192, B2, tid);        // Vca
            __syncthreads();
        }

        // ================= DECODER CROSS-ATTN (kv from mem R0) ============
        {
            int st = pass * 3 + 3;
            float4* Gx = (st & 1) ? kvx1 : kvx0;
            kv_gemm(R0, B1, B2, Bca, b, base, KVs, Gx, tid);
            ldwp<64, 64, 68>(Wca, B0, tid);               // Qca
            flag_pub(flagme, st, tid);
            q_gemm(R3, B0, Bca, R1, tid);
            ldwp<64, 64, 68>(Wcao, B1, tid);              // OUTca
            kv_wait(flagpt, st, Gx, b, pbase, KVs, tid);
            attn_block(R1, KVs, tid);
            ldwp<64, 16, 20>(Wdl1, B2, tid);              // FFN1d
            __syncthreads();
            out_res(R1, B1, Bcao, R3, tid);
            ldwp<16, 64, 68>(Wdl2, B0, tid);              // FFN2d
            __syncthreads();
            // FFN1: R3 -> Hs  |  stage Wf->B1
            if (tid < 200) {
                const int r = tid >> 2, c4 = tid & 3;
                float a[4] = {0, 0, 0, 0};
                gemm14v<64, 20>(R3 + r * 68, B2 + 4 * c4, a);
                v4f bb = *reinterpret_cast<const v4f*>(Bdl1 + 4 * c4);
                *reinterpret_cast<v4f*>(Hs + r * 20 + 4 * c4) =
                    (v4f){a[0] + bb[0], a[1] + bb[1], a[2] + bb[2], a[3] + bb[3]};
            }
            ldwp<64, 32, 36>(Wf, B1, tid);
            __syncthreads();
            // FFN2: Hs -> R3 (+res)
            if (tid < 400) {
                const int r0 = tid >> 4, cg = tid & 15;
                v2f acc[4] = {};
                gemm_dual24<16, 68>(Hs + r0 * 20, Hs + (r0 + 25) * 20, B0 + 4 * cg, acc);
                v4f bb = *reinterpret_cast<const v4f*>(Bdl2 + 4 * cg);
#pragma unroll
                for (int rr = 0; rr < 2; ++rr) {
                    float* xp = R3 + (r0 + 25 * rr) * 68 + 4 * cg;
                    v4f u = *reinterpret_cast<v4f*>(xp);
                    *reinterpret_cast<v4f*>(xp) =
                        (v4f){acc[0][rr] + bb[0] + u[0], acc[1][rr] + bb[1] + u[1],
                              acc[2][rr] + bb[2] + u[2], acc[3][rr] + bb[3] + u[3]};
                }
            }
            __syncthreads();
            // head: sigmoid(R3 @ Wf^T + bf) -> out (+ X1s for pass1's c)
            if (tid < 400) {
                const int r = tid >> 3, lp = tid & 7;
                float a[4] = {0, 0, 0, 0};
                gemm14v<64, 36>(R3 + r * 68, B1 + 4 * lp, a);
                v4f bb = *reinterpret_cast<const v4f*>(Bf + 4 * lp);
                v4f o;
#pragma unroll
                for (int c = 0; c < 4; ++c) o[c] = 1.f / (1.f + __expf(-(a[c] + bb[c])));
                int rg = base + r;
                *reinterpret_cast<v4f*>(outx + ((size_t)rg * 128 + b) * 32 + 4 * lp) = o;
                if (pass == 0)
                    *reinterpret_cast<v4f*>(X1s + r * 36 + 4 * lp) = o;
            }
        }
    }
}

// ---------------------------------------------------------------------------
extern "C" void kernel_launch(void* const* d_in, const int* in_sizes, int n_in,
                              void* d_out, int out_size, void* d_ws, size_t ws_size,
                              hipStream_t stream)
{
    KParams prm;
    for (int i = 0; i < 36; ++i) prm.p[i] = d_in[i];
    float4* kvx0 = (float4*)d_ws;                 // 409600 float4 = 6.55 MB
    float4* kvx1 = kvx0 + 409600;                 // parity double-buffer
    int* flags = (int*)(kvx1 + 409600);           // 256 flags, 128B apart
    k_fused<<<dim3(256), dim3(TPB), 0, stream>>>(prm, (float*)d_out, kvx0, kvx1, flags);
}

// Round 9
// 181.339 us; speedup vs baseline: 1.0808x; 1.0808x over previous
//
#include <hip/hip_runtime.h>
#include <math.h>

// TranAD fused forward, 2 blocks per batch element (grid=256, 1024 thr).
// Round-9: attention key-axis parallelization. r5-r8 showed GEMM restructures
// are neutral -- the dominant untouched term is attention: 416 threads x
// (100 keys x 4 q) with ~400 serial transcendentals each, ~6 stages. Now:
// task = (head, 4q, key-half) = 832 threads, 50 keys each, pair-merged via
// __shfl_xor online-softmax rescale (same wave, lockstep, no barrier).
// FFN1 widened 200->800 thr. Rest identical to round-7 (188us, verified).
// Exchange via sc0 sc1 IF$-coherent ops; co-residency: 137.5KB LDS =>
// 1 block/CU => all 256 blocks resident => pairwise spin cannot deadlock.

#define TPB 1024
#define RH 50
#define SQ32 5.656854249492381f

#ifndef __has_builtin
#define __has_builtin(x) 0
#endif
#if __has_builtin(__builtin_amdgcn_exp2f)
#define EXP2(x) __builtin_amdgcn_exp2f(x)
#else
#define EXP2(x) exp2f(x)
#endif

typedef float v2f __attribute__((ext_vector_type(2)));
typedef float v4f __attribute__((ext_vector_type(4)));

struct KParams { const void* p[36]; };

// ---- stage W[MC][K] (row-major) transposed into Ws[k*WP + moff + m] ----
template<int K, int MC, int WP>
__device__ __forceinline__ void ldwp(const float* __restrict__ Wt, float* __restrict__ Ws,
                                     int moff, int tid)
{
    for (int i = tid; i < MC * K; i += TPB) {
        int m = i / K, k = i - m * K;       // K is 2^n -> shifts
        Ws[k * WP + moff + m] = Wt[i];
    }
}

// ---- 2 rows x 4 cols, x as v4f, weights LDS [k][*] pitch WP ----
template<int K, int WP>
__device__ __forceinline__ void gemm_dual24(const float* __restrict__ x0,
                                            const float* __restrict__ x1,
                                            const float* __restrict__ w, v2f acc[4])
{
#pragma unroll 4
    for (int kk = 0; kk < K / 4; ++kk) {
        v4f xa = *reinterpret_cast<const v4f*>(x0 + 4 * kk);
        v4f xb = *reinterpret_cast<const v4f*>(x1 + 4 * kk);
#pragma unroll
        for (int j = 0; j < 4; ++j) {
            v4f wv = *reinterpret_cast<const v4f*>(w + (size_t)(4 * kk + j) * WP);
            v2f xj = {xa[j], xb[j]};
#pragma unroll
            for (int c = 0; c < 4; ++c) {
                v2f wc = {wv[c], wv[c]};
                acc[c] = __builtin_elementwise_fma(xj, wc, acc[c]);
            }
        }
    }
}

// ---- 1 row x 4 cols, x as v4f ----
template<int K, int WP>
__device__ __forceinline__ void gemm14v(const float* __restrict__ x,
                                        const float* __restrict__ w, float acc[4])
{
#pragma unroll 4
    for (int kk = 0; kk < K / 4; ++kk) {
        v4f xv = *reinterpret_cast<const v4f*>(x + 4 * kk);
#pragma unroll
        for (int j = 0; j < 4; ++j) {
            v4f wv = *reinterpret_cast<const v4f*>(w + (size_t)(4 * kk + j) * WP);
#pragma unroll
            for (int c = 0; c < 4; ++c) acc[c] = fmaf(xv[j], wv[c], acc[c]);
        }
    }
}

// ---------------------------------------------------------------------------
// KV projection: 800 thr (tid<400: K chunk, 400..799: V chunk), 2 rows each.
// Writes interleaved KVs[h][101] (k->xy, v->zw) + direct sc0sc1 exchange store.
// ---------------------------------------------------------------------------
__device__ __forceinline__ void kv_gemm(const float* __restrict__ Xkv,
    const float* __restrict__ RW, const float* __restrict__ Bqkv,
    int b, int base, float4* __restrict__ KVs, float4* __restrict__ Gx, int tid)
{
    if (tid >= 800) return;
    const int isV = tid >= 400;
    const int u = tid - (isV ? 400 : 0);
    const int r0 = u >> 4, cg = u & 15;
    v2f acc[4] = {};
    gemm_dual24<64, 132>(Xkv + r0 * 68, Xkv + (r0 + 25) * 68,
                         RW + (isV ? 64 : 0) + 4 * cg, acc);
    v4f bb = *reinterpret_cast<const v4f*>(Bqkv + (isV ? 128 : 64) + 4 * cg);
    const int h0 = 2 * cg;
    const int off = isV ? 2 : 0;
#pragma unroll
    for (int rr = 0; rr < 2; ++rr) {
        int sg = base + r0 + 25 * rr;
        v2f p0 = {acc[0][rr] + bb[0], acc[1][rr] + bb[1]};
        v2f p1 = {acc[2][rr] + bb[2], acc[3][rr] + bb[3]};
        *reinterpret_cast<v2f*>(reinterpret_cast<float*>(KVs + h0 * 101 + sg) + off) = p0;
        *reinterpret_cast<v2f*>(reinterpret_cast<float*>(KVs + (h0 + 1) * 101 + sg) + off) = p1;
        float* g0 = reinterpret_cast<float*>(Gx + ((size_t)b * 100 + sg) * 32 + h0) + off;
        float* g1 = reinterpret_cast<float*>(Gx + ((size_t)b * 100 + sg) * 32 + h0 + 1) + off;
        asm volatile("global_store_dwordx2 %0, %1, off sc0 sc1" :: "v"(g0), "v"(p0) : "memory");
        asm volatile("global_store_dwordx2 %0, %1, off sc0 sc1" :: "v"(g1), "v"(p1) : "memory");
    }
}

// drain own sc0sc1 stores, barrier, raise flag
__device__ __forceinline__ void flag_pub(int* flagme, int st, int tid)
{
    asm volatile("s_waitcnt vmcnt(0)" ::: "memory");
    __syncthreads();
    if (tid == 0)
        asm volatile("global_store_dword %0, %1, off sc0 sc1" :: "v"(flagme), "v"(st) : "memory");
}

// q projection (chunk 0 of staged RW), 400 thr, 2 rows each -> R1
__device__ __forceinline__ void q_gemm(const float* __restrict__ Xq,
    const float* __restrict__ RW, const float* __restrict__ Bqkv,
    float* __restrict__ Q, int tid)
{
    if (tid >= 400) return;
    const int r0 = tid >> 4, cg = tid & 15;
    v2f acc[4] = {};
    gemm_dual24<64, 132>(Xq + r0 * 68, Xq + (r0 + 25) * 68, RW + 4 * cg, acc);
    v4f bb = *reinterpret_cast<const v4f*>(Bqkv + 4 * cg);
#pragma unroll
    for (int rr = 0; rr < 2; ++rr)
        *reinterpret_cast<v4f*>(Q + (r0 + 25 * rr) * 68 + 4 * cg) =
            (v4f){acc[0][rr] + bb[0], acc[1][rr] + bb[1],
                  acc[2][rr] + bb[2], acc[3][rr] + bb[3]};
}

// spin (relaxed sc0sc1, no cache maintenance), then pull partner half into LDS
__device__ __forceinline__ void kv_wait(const int* flagpt, int st,
    const float4* __restrict__ Gx, int b, int pbase,
    float4* __restrict__ KVs, int tid)
{
    if (tid == 0) {
        int f;
        for (;;) {
            asm volatile("global_load_dword %0, %1, off sc0 sc1\n\ts_waitcnt vmcnt(0)"
                         : "=v"(f) : "v"(flagpt) : "memory");
            if (f >= st) break;
            __builtin_amdgcn_s_sleep(8);
        }
    }
    __syncthreads();
    const int i2 = tid + 1024;
    v4f a1, a2;
    const float4* p1 = Gx + ((size_t)b * 100 + pbase + (tid >> 5)) * 32 + (tid & 31);
    asm volatile("global_load_dwordx4 %0, %1, off sc0 sc1" : "=v"(a1) : "v"(p1) : "memory");
    if (i2 < 1600) {
        const float4* p2 = Gx + ((size_t)b * 100 + pbase + (i2 >> 5)) * 32 + (i2 & 31);
        asm volatile("global_load_dwordx4 %0, %1, off sc0 sc1" : "=v"(a2) : "v"(p2) : "memory");
    }
    asm volatile("s_waitcnt vmcnt(0)" ::: "memory");
    *reinterpret_cast<v4f*>(KVs + (tid & 31) * 101 + pbase + (tid >> 5)) = a1;
    if (i2 < 1600)
        *reinterpret_cast<v4f*>(KVs + (i2 & 31) * 101 + pbase + (i2 >> 5)) = a2;
    __syncthreads();
}

// ---------------------------------------------------------------------------
// attention v2: own 50 q-rows, full 100-key KV.
// task = (head, 4-query group, KEY-HALF): 832 threads, 50 keys each.
// Pair lanes (tid^1, same wave) merge partials via shfl_xor + online rescale.
// ---------------------------------------------------------------------------
__device__ __forceinline__ void attn_block(float* __restrict__ Q,
                                           const float4* __restrict__ KVs, int tid)
{
    if (tid < 832) {
        const int u = tid >> 1, sh = tid & 1;
        const int h = u / 13;
        const int g = u - 13 * h;
        const int lq0 = 4 * g;
        const float4* kv = KVs + h * 101 + sh * 50;
        const float SCALE = 0.7071067811865476f * 1.4426950408889634f;  // /sqrt(2)*log2e
        float q0[4], q1[4];
#pragma unroll
        for (int j = 0; j < 4; ++j) {
            if (lq0 + j < RH) {
                float2 qv = *reinterpret_cast<const float2*>(Q + (lq0 + j) * 68 + 2 * h);
                q0[j] = qv.x * SCALE; q1[j] = qv.y * SCALE;
            } else { q0[j] = 0.f; q1[j] = 0.f; }
        }
        float mx[4] = {-1e30f, -1e30f, -1e30f, -1e30f};
#pragma unroll 5
        for (int s = 0; s < 50; ++s) {
            float4 k = kv[s];
#pragma unroll
            for (int j = 0; j < 4; ++j)
                mx[j] = fmaxf(mx[j], fmaf(q0[j], k.x, q1[j] * k.y));
        }
        float sum[4] = {0, 0, 0, 0}, a0[4] = {0, 0, 0, 0}, a1[4] = {0, 0, 0, 0};
#pragma unroll 5
        for (int s = 0; s < 50; ++s) {
            float4 k = kv[s];
#pragma unroll
            for (int j = 0; j < 4; ++j) {
                float e = EXP2(fmaf(q0[j], k.x, fmaf(q1[j], k.y, -mx[j])));
                sum[j] += e;
                a0[j] = fmaf(e, k.z, a0[j]);
                a1[j] = fmaf(e, k.w, a1[j]);
            }
        }
        // merge with pair lane (other key-half), online-softmax rescale
#pragma unroll
        for (int j = 0; j < 4; ++j) {
            float mo = __shfl_xor(mx[j], 1);
            float so = __shfl_xor(sum[j], 1);
            float ao = __shfl_xor(a0[j], 1);
            float bo = __shfl_xor(a1[j], 1);
            float m = fmaxf(mx[j], mo);
            float c1 = EXP2(mx[j] - m), c2 = EXP2(mo - m);
            float S = fmaf(sum[j], c1, so * c2);
            float A = fmaf(a0[j], c1, ao * c2);
            float B = fmaf(a1[j], c1, bo * c2);
            if (sh == 0 && lq0 + j < RH) {
                float inv = 1.f / S;
                *reinterpret_cast<float2*>(Q + (lq0 + j) * 68 + 2 * h) =
                    make_float2(A * inv, B * inv);
            }
        }
    }
}

// out-projection + residual in place, 400 thr, 2 rows each
__device__ __forceinline__ void out_res(const float* __restrict__ Ain,
    const float* __restrict__ RW, const float* __restrict__ Bi,
    float* __restrict__ Sres, int tid)
{
    if (tid >= 400) return;
    const int r0 = tid >> 4, cg = tid & 15;
    v2f acc[4] = {};
    gemm_dual24<64, 132>(Ain + r0 * 68, Ain + (r0 + 25) * 68, RW + 4 * cg, acc);
    v4f bb = *reinterpret_cast<const v4f*>(Bi + 4 * cg);
#pragma unroll
    for (int rr = 0; rr < 2; ++rr) {
        float* sp = Sres + (r0 + 25 * rr) * 68 + 4 * cg;
        v4f s0 = *reinterpret_cast<v4f*>(sp);
        *reinterpret_cast<v4f*>(sp) =
            (v4f){acc[0][rr] + bb[0] + s0[0], acc[1][rr] + bb[1] + s0[1],
                  acc[2][rr] + bb[2] + s0[2], acc[3][rr] + bb[3] + s0[3]};
    }
}

// ---------------------------------------------------------------------------
__global__ __launch_bounds__(TPB) void k_fused(KParams prm, float* __restrict__ outp,
    float4* __restrict__ kvx0, float4* __restrict__ kvx1, int* __restrict__ flags)
{
    __shared__ float R0[RH * 68];        // s / mem
    __shared__ float R1[RH * 68];        // q / attn-out
    __shared__ float R3[RH * 68];        // t
    __shared__ float4 KVs[32 * 101];     // full-seq KV interleaved (k.xy, v.zw)
    __shared__ float RW[64 * 132];       // staged weights (K|V side-by-side)
    __shared__ float Hs[RH * 20];        // FFN hidden
    __shared__ float X1s[RH * 36];       // x1 pass0 -> pass1

    const int tid = threadIdx.x;
    const int b = blockIdx.x & 127;
    const int half = blockIdx.x >> 7;
    const int base = half * RH;
    const int pbase = RH - base;
    int* flagme = flags + (b * 2 + half) * 32;
    int* flagpt = flags + (b * 2 + 1 - half) * 32;

    const float* src = (const float*)prm.p[0];
    const float* tgt = (const float*)prm.p[1];

#define ATT_STAGE(Xq, Xkv, WQKV, BQ, WOUT, BO, SRES, st)                     \
    {                                                                        \
        float4* Gx = ((st) & 1) ? kvx1 : kvx0;                               \
        __syncthreads();              /* RW free, Xkv ready */               \
        ldwp<64, 64, 132>((WQKV) + 4096, RW, 0, tid);   /* K chunk */        \
        ldwp<64, 64, 132>((WQKV) + 8192, RW, 64, tid);  /* V chunk */        \
        __syncthreads();                                                     \
        kv_gemm(Xkv, RW, BQ, b, base, KVs, Gx, tid);                         \
        flag_pub(flagme, st, tid);    /* vmcnt + barrier + flag */           \
        ldwp<64, 64, 132>(WQKV, RW, 0, tid);            /* Q chunk */        \
        __syncthreads();                                                     \
        q_gemm(Xq, RW, BQ, R1, tid);                                         \
        kv_wait(flagpt, st, Gx, b, pbase, KVs, tid);                         \
        attn_block(R1, KVs, tid);                                            \
        __syncthreads();                                                     \
        ldwp<64, 64, 132>(WOUT, RW, 0, tid);                                 \
        __syncthreads();                                                     \
        out_res(R1, RW, BO, SRES, tid);                                      \
    }

#define FFN_STAGE(X, W1, B1, W2, B2)                                         \
    {                                                                        \
        __syncthreads();              /* X final, RW free */                 \
        ldwp<64, 16, 20>(W1, RW, 0, tid);                                    \
        __syncthreads();                                                     \
        if (tid < 800) {              /* 50 rows x 16 cols, 1 out/thread */  \
            const int r = tid >> 4, c = tid & 15;                            \
            float a = (B1)[c];                                               \
            const float* xrow = (X) + r * 68;                                \
            _Pragma("unroll 4")                                              \
            for (int kk = 0; kk < 16; ++kk) {                                \
                v4f xv = *reinterpret_cast<const v4f*>(xrow + 4 * kk);       \
                _Pragma("unroll")                                            \
                for (int j = 0; j < 4; ++j)                                  \
                    a = fmaf(xv[j], RW[(4 * kk + j) * 20 + c], a);           \
            }                                                                \
            Hs[r * 20 + c] = a;                                              \
        }                                                                    \
        __syncthreads();                                                     \
        ldwp<16, 64, 68>(W2, RW, 0, tid);                                    \
        __syncthreads();                                                     \
        if (tid < 400) {                                                     \
            const int r0 = tid >> 4, cg = tid & 15;                          \
            v2f acc[4] = {};                                                 \
            gemm_dual24<16, 68>(Hs + r0 * 20, Hs + (r0 + 25) * 20,           \
                                RW + 4 * cg, acc);                           \
            v4f bb = *reinterpret_cast<const v4f*>((B2) + 4 * cg);           \
            _Pragma("unroll")                                                \
            for (int rr = 0; rr < 2; ++rr) {                                 \
                float* xp = (X) + (r0 + 25 * rr) * 68 + 4 * cg;              \
                v4f u = *reinterpret_cast<v4f*>(xp);                         \
                *reinterpret_cast<v4f*>(xp) =                                \
                    (v4f){acc[0][rr] + bb[0] + u[0], acc[1][rr] + bb[1] + u[1], \
                          acc[2][rr] + bb[2] + u[2], acc[3][rr] + bb[3] + u[3]}; \
            }                                                                \
        }                                                                    \
        __syncthreads();                                                     \
    }

    for (int pass = 0; pass < 2; ++pass) {
        const float* Wq_enc = (const float*)prm.p[2];
        const float* Beq    = (const float*)prm.p[3];
        const float* Wo_enc = (const float*)prm.p[4];
        const float* Beo    = (const float*)prm.p[5];
        const float* Wel1   = (const float*)prm.p[22];
        const float* Bel1   = (const float*)prm.p[23];
        const float* Wel2   = (const float*)prm.p[24];
        const float* Bel2   = (const float*)prm.p[25];
        const float* Wsa    = (const float*)prm.p[pass ? 14 : 6];
        const float* Bsa    = (const float*)prm.p[pass ? 15 : 7];
        const float* Wsao   = (const float*)prm.p[pass ? 16 : 8];
        const float* Bsao   = (const float*)prm.p[pass ? 17 : 9];
        const float* Wca    = (const float*)prm.p[pass ? 18 : 10];
        const float* Bca    = (const float*)prm.p[pass ? 19 : 11];
        const float* Wcao   = (const float*)prm.p[pass ? 20 : 12];
        const float* Bcao   = (const float*)prm.p[pass ? 21 : 13];
        const float* Wdl1   = (const float*)prm.p[pass ? 30 : 26];
        const float* Bdl1   = (const float*)prm.p[pass ? 31 : 27];
        const float* Wdl2   = (const float*)prm.p[pass ? 32 : 28];
        const float* Bdl2   = (const float*)prm.p[pass ? 33 : 29];
        const float* Wf     = (const float*)prm.p[34];
        const float* Bf     = (const float*)prm.p[35];
        float* outx = outp + (pass ? 409600 : 0);

        // ---- build s -> R0, tile tgt -> R3 ----
        __syncthreads();        // X1s (pass0 head) read; R0/R3/RW reuse
        for (int i = tid; i < RH * 64; i += TPB) {
            int l = i >> 6, d = i & 63;
            int lg = base + l;
            float sv = src[((size_t)lg * 128 + b) * 32 + (d & 31)];
            float v;
            if (d < 32) v = sv;
            else if (pass == 0) v = 0.f;
            else { float df = X1s[l * 36 + (d - 32)] - sv; v = df * df; }
            float div = __expf((float)d * -0.14391156831212787f);
            float pe = 1.4142135623730951f * __sinf((float)lg * div + 0.7853981633974483f);
            R0[l * 68 + d] = v * SQ32 + pe;
        }
        for (int i = tid; i < RH * 8; i += TPB) {
            int l = i >> 3, q4 = i & 7;
            int lg = base + l;
            float4 tv = *reinterpret_cast<const float4*>(tgt + ((size_t)lg * 128 + b) * 32 + 4 * q4);
            *reinterpret_cast<float4*>(R3 + l * 68 + 4 * q4) = tv;
            *reinterpret_cast<float4*>(R3 + l * 68 + 32 + 4 * q4) = tv;
        }

        // ---- encoder self-attention + FFN (R0 becomes mem) ----
        ATT_STAGE(R0, R0, Wq_enc, Beq, Wo_enc, Beo, R0, pass * 3 + 1)
        FFN_STAGE(R0, Wel1, Bel1, Wel2, Bel2)

        // ---- decoder self-attention ----
        ATT_STAGE(R3, R3, Wsa, Bsa, Wsao, Bsao, R3, pass * 3 + 2)

        // ---- decoder cross-attention (q from t, kv from mem) ----
        ATT_STAGE(R3, R0, Wca, Bca, Wcao, Bcao, R3, pass * 3 + 3)
        FFN_STAGE(R3, Wdl1, Bdl1, Wdl2, Bdl2)

        // ---- head: sigmoid(R3 @ Wf^T + bf) -> out (+ X1s for pass1's c) ----
        ldwp<64, 32, 36>(Wf, RW, 0, tid);    // FFN_STAGE ended with barrier
        __syncthreads();
        if (tid < 400) {
            const int r = tid >> 3, lp = tid & 7;
            float a[4] = {0, 0, 0, 0};
            gemm14v<64, 36>(R3 + r * 68, RW + 4 * lp, a);
            v4f bb = *reinterpret_cast<const v4f*>(Bf + 4 * lp);
            v4f o;
#pragma unroll
            for (int c = 0; c < 4; ++c) o[c] = 1.f / (1.f + __expf(-(a[c] + bb[c])));
            int rg = base + r;
            *reinterpret_cast<v4f*>(outx + ((size_t)rg * 128 + b) * 32 + 4 * lp) = o;
            if (pass == 0)
                *reinterpret_cast<v4f*>(X1s + r * 36 + 4 * lp) = o;
        }
    }
#undef ATT_STAGE
#undef FFN_STAGE
}

// ---------------------------------------------------------------------------
extern "C" void kernel_launch(void* const* d_in, const int* in_sizes, int n_in,
                              void* d_out, int out_size, void* d_ws, size_t ws_size,
                              hipStream_t stream)
{
    KParams prm;
    for (int i = 0; i < 36; ++i) prm.p[i] = d_in[i];
    float4* kvx0 = (float4*)d_ws;                 // 409600 float4 = 6.55 MB
    float4* kvx1 = kvx0 + 409600;                 // parity double-buffer
    int* flags = (int*)(kvx1 + 409600);           // 256 flags, 128B apart
    k_fused<<<dim3(256), dim3(TPB), 0, stream>>>(prm, (float*)d_out, kvx0, kvx1, flags);
}